// Round 17
// baseline (62.264 us; speedup 1.0000x reference)
//
#include <hip/hip_runtime.h>

// B*H*W = 65536 vectors, dim 64, 512 codes
#define NVEC 65536
#define DIM 64
#define KCODES 512
#define VPB 128       // vectors per block
#define NBLK 512      // NVEC / VPB
#define ELS 2048.0f   // residual pre-scale (avoids fp16 denormals)
#define INV_ELS (1.0f / 2048.0f)
#define BIAS 8.0f     // score bias -> positive floats, uint-sortable
#define GAP_THR 2.5e-4f // rescore guard: > 2x (split-fp16 1.5e-5 + 5-bit mask 3e-5)

typedef _Float16 f16x8 __attribute__((ext_vector_type(8)));
typedef float    f32x4 __attribute__((ext_vector_type(4)));
typedef unsigned long long u64;

// ws layout (floats): ws[0] = block-completion counter (uint, zeroed by prep)
#define WS_EN   4                   // [4..516) codebook norms (exact)
#define WS_EH   1024                // [1024..17408) hi fp16 B-fragments (pre-scaled by -2)
#define WS_EL   (1024 + 16384)      // [17408..33792) residual fp16 B-fragments (pre-scaled by -2*ELS)
#define WS_PART 33792               // [33792..34304) per-block loss partials (512)
#define WS_EMBT 34816               // [34816..67584) embT[k][d]

// Prep (17 blocks x 512): b=0 exact norms + zero the completion counter;
// b=1..8 MFMA B-fragments with -2 folded in; b=9..16 emb -> embT.
__global__ __launch_bounds__(512, 1) void prep_kernel(const float* __restrict__ emb,
                                                      float* __restrict__ ws) {
    const int tid = threadIdx.x;
    const int b   = blockIdx.x;
    if (b == 0) {
        if (tid == 0) ((unsigned*)ws)[0] = 0u;   // completion counter
        float s = 0.f;
#pragma unroll
        for (int d = 0; d < DIM; ++d) { float v = emb[d * KCODES + tid]; s = fmaf(v, v, s); }
        ws[WS_EN + tid] = s;
    } else if (b <= 8) {
        const int fl = (b - 1) * 512 + tid;            // fragment-lane id, 0..4095
        const int ct = fl >> 7, s5 = (fl >> 6) & 1, l = fl & 63;
        const int k  = ct * 16 + (l & 15);             // B col
        const int d0 = s5 * 32 + (l >> 4) * 8;         // B k-rows (d)
        f16x8 eh, el;
#pragma unroll
        for (int e = 0; e < 8; ++e) {
            float v = emb[(d0 + e) * KCODES + k];
            _Float16 h = (_Float16)v;
            _Float16 l16 = (_Float16)((v - (float)h) * ELS);
            eh[e] = -(h + h);      // -2*h, exact
            el[e] = -(l16 + l16);  // -2*l, exact
        }
        ((f16x8*)(ws + WS_EH))[fl] = eh;
        ((f16x8*)(ws + WS_EL))[fl] = el;
    } else {
        __shared__ float tl[64][65];
        const int kt = b - 9;          // k-tile 0..7
        const int r  = tid >> 3;       // 0..63
        const int g  = tid & 7;
#pragma unroll
        for (int i = 0; i < 8; ++i)
            tl[r][g * 8 + i] = emb[r * KCODES + kt * 64 + g * 8 + i];
        __syncthreads();
#pragma unroll
        for (int i = 0; i < 8; ++i)
            ws[WS_EMBT + (kt * 64 + r) * 64 + g * 8 + i] = tl[g * 8 + i][r];
    }
}

// Main: 512 thr = 8 waves, VPB=128, grid 512 -> 4 waves/SIMD, one round.
// R15 scan verbatim (packed-u32 top-2, swap-free 2-deep pipeline, u64 lex
// merge, GAP_THR exact rescore, embT epilogue) with two overhead cuts:
// (1) A-fragments built DIRECTLY from global x per lane (no LDS round-trip,
// no pack pass, 2 fewer barriers); (2) loss finished in-kernel by the last
// block (one counter atomic per block; finish kernel deleted).
__global__ __launch_bounds__(512, 2) void vq_kernel(const float* __restrict__ x,
                                                    const float* __restrict__ ws_ro,
                                                    float* __restrict__ out,
                                                    float* __restrict__ ws) {
    __shared__ float enS8[KCODES];  // en + BIAS (scan C-init)
    __shared__ int   cand[VPB][2];
    __shared__ float sdfm[VPB][2];  // biased masked scores
    __shared__ float exd[VPB][2];
    __shared__ int   bksel[VPB];
    __shared__ float swl[8];
    __shared__ int   lastFlag;

    const int tid  = threadIdx.x;
    const int wid  = tid >> 6;            // 0..7
    const int lane = tid & 63;
    const size_t xbase = (size_t)blockIdx.x * VPB * DIM;

    enS8[tid] = ws_ro[WS_EN + tid] + BIAS;   // biased copy for the scan

    // A-fragments directly from global x: lane owns row vA, dims
    // [g4*8, g4*8+8) and [32+g4*8, +8) -> 4x float4, convert in regs.
    const int vb  = wid * 16;
    const int col = lane & 15;
    const int g4  = lane >> 4;
    const int vA  = vb + col;
    f16x8 ah0, al0, ah1, al1;
    {
        const float* xr = x + xbase + (size_t)vA * DIM + g4 * 8;
        float4 q0 = *(const float4*)(xr);
        float4 q1 = *(const float4*)(xr + 4);
        float4 q2 = *(const float4*)(xr + 32);
        float4 q3 = *(const float4*)(xr + 36);
        float t0[8] = {q0.x, q0.y, q0.z, q0.w, q1.x, q1.y, q1.z, q1.w};
        float t1[8] = {q2.x, q2.y, q2.z, q2.w, q3.x, q3.y, q3.z, q3.w};
#pragma unroll
        for (int i = 0; i < 8; ++i) {
            _Float16 h = (_Float16)t0[i];
            ah0[i] = h;
            al0[i] = (_Float16)((t0[i] - (float)h) * ELS);
            _Float16 g = (_Float16)t1[i];
            ah1[i] = g;
            al1[i] = (_Float16)((t1[i] - (float)g) * ELS);
        }
    }

    const f16x8* ehp = (const f16x8*)(ws_ro + WS_EH);
    const f16x8* elp = (const f16x8*)(ws_ro + WS_EL);

    unsigned b1[4] = {~0u, ~0u, ~0u, ~0u};
    unsigned b2[4] = {~0u, ~0u, ~0u, ~0u};

    // swap-free 2-deep pipeline: sets A (even tiles) and B (odd tiles)
    f16x8 Ah0 = ehp[lane],        Ah1 = ehp[64 + lane];
    f16x8 Al0 = elp[lane],        Al1 = elp[64 + lane];
    f16x8 Bh0 = ehp[128 + lane],  Bh1 = ehp[192 + lane];
    f16x8 Bl0 = elp[128 + lane],  Bl1 = elp[192 + lane];
    int onx = 256 + lane;                 // fragment index of tile ct+2

    __syncthreads();                      // enS8 ready

#define COMPUTE(T, H0, H1, L0, L1) { \
        const float enk8 = enS8[(T) * 16 + col]; \
        f32x4 acch  = {enk8, enk8, enk8, enk8}; \
        f32x4 accm1 = {0.f, 0.f, 0.f, 0.f}; \
        f32x4 accm2 = {0.f, 0.f, 0.f, 0.f}; \
        acch  = __builtin_amdgcn_mfma_f32_16x16x32_f16(ah0, H0, acch,  0, 0, 0); \
        acch  = __builtin_amdgcn_mfma_f32_16x16x32_f16(ah1, H1, acch,  0, 0, 0); \
        accm1 = __builtin_amdgcn_mfma_f32_16x16x32_f16(al0, H0, accm1, 0, 0, 0); \
        accm1 = __builtin_amdgcn_mfma_f32_16x16x32_f16(ah0, L0, accm1, 0, 0, 0); \
        accm2 = __builtin_amdgcn_mfma_f32_16x16x32_f16(al1, H1, accm2, 0, 0, 0); \
        accm2 = __builtin_amdgcn_mfma_f32_16x16x32_f16(ah1, L1, accm2, 0, 0, 0); \
        _Pragma("unroll") \
        for (int j = 0; j < 4; ++j) { \
            float scb = fmaf(accm1[j] + accm2[j], INV_ELS, acch[j]); \
            unsigned u = (__float_as_uint(scb) & 0xFFFFFFE0u) | (unsigned)(T); \
            b2[j] = min(b2[j], max(u, b1[j])); \
            b1[j] = min(b1[j], u); \
        } }

#pragma unroll 1
    for (int ct = 0; ct < 32; ct += 2) {
        COMPUTE(ct, Ah0, Ah1, Al0, Al1)
        // reload set A with tile ct+2 (tail iters read harmless ws data)
        Ah0 = ehp[onx]; Ah1 = ehp[onx + 64];
        Al0 = elp[onx]; Al1 = elp[onx + 64];
        COMPUTE(ct + 1, Bh0, Bh1, Bl0, Bl1)
        Bh0 = ehp[onx + 128]; Bh1 = ehp[onx + 192];
        Bl0 = elp[onx + 128]; Bl1 = elp[onx + 192];
        onx += 256;
    }
#undef COMPUTE

    // rebuild (masked-dist, k) as u64 and lex-merge top-2 across 16 lanes
    u64 q1[4], q2[4];
#pragma unroll
    for (int j = 0; j < 4; ++j) {
        q1[j] = ((u64)(b1[j] & 0xFFFFFFE0u) << 32) | (unsigned)((b1[j] & 31u) * 16 + col);
        q2[j] = ((u64)(b2[j] & 0xFFFFFFE0u) << 32) | (unsigned)((b2[j] & 31u) * 16 + col);
    }
#pragma unroll
    for (int m = 1; m <= 8; m <<= 1) {
#pragma unroll
        for (int j = 0; j < 4; ++j) {
            u64 qa = __shfl_xor(q1[j], m);
            u64 qb = __shfl_xor(q2[j], m);
            u64 lo = q1[j] < qa ? q1[j] : qa;
            u64 hi = q1[j] < qa ? qa : q1[j];
            u64 s2 = q2[j] < qb ? q2[j] : qb;
            q1[j] = lo;
            q2[j] = hi < s2 ? hi : s2;
        }
    }
    {
        const int j = lane & 15;
        if (j < 4) {                      // static-index extraction (rule #20)
            const int v = vb + g4 * 4 + j;
            u64 s1 = j == 0 ? q1[0] : j == 1 ? q1[1] : j == 2 ? q1[2] : q1[3];
            u64 s2 = j == 0 ? q2[0] : j == 1 ? q2[1] : j == 2 ? q2[2] : q2[3];
            sdfm[v][0] = __uint_as_float((unsigned)(s1 >> 32));  // biased, masked
            sdfm[v][1] = __uint_as_float((unsigned)(s2 >> 32));
            cand[v][0] = (int)(s1 & 0x1FFu);
            cand[v][1] = (int)(s2 & 0x1FFu);
        }
    }
    __syncthreads();

    // conditional exact rescore (reference-exact chain; exact en from ws)
    if (tid < 2 * VPB) {
        const int v = tid >> 1, cc = tid & 1;
        float res = sdfm[v][cc];          // biased fallback (consistent pair)
        if (sdfm[v][1] - sdfm[v][0] <= GAP_THR) {
            const int k = cand[v][cc];
            const float* xr = x + xbase + v * DIM;
            const float* er = ws_ro + WS_EMBT + k * 64;
            float zn = 0.f, dot = 0.f;
#pragma unroll
            for (int d = 0; d < DIM; ++d) {
                float xv = xr[d];
                zn  = fmaf(xv, xv, zn);
                dot = fmaf(xv, er[d], dot);
            }
            res = fmaf(-2.0f, dot, zn + ws_ro[WS_EN + k]);
        }
        exd[v][cc] = res;
    }
    __syncthreads();
    if (tid < VPB) {
        const int k0 = cand[tid][0], k1 = cand[tid][1];
        const float d0 = exd[tid][0], d1 = exd[tid][1];
        const bool take2 = (d1 < d0) || (d1 == d0 && k1 < k0);
        bksel[tid] = take2 ? k1 : k0;
    }
    __syncthreads();

    // epilogue: thread -> (vector v16, dim-block j16); q from embT rows
    const int v16 = tid >> 2;             // 0..127
    const int j16 = (tid & 3) * 16;
    const int bk  = bksel[v16];
    const int gvec = blockIdx.x * VPB + v16;
    const float*  xg  = x + (size_t)gvec * DIM + j16;
    float*        og  = out + (size_t)gvec * DIM + j16;
    const float4* et4 = (const float4*)(ws_ro + WS_EMBT + bk * 64);

    float lossLocal = 0.f;
#pragma unroll
    for (int c = 0; c < 4; ++c) {
        float4 q  = et4[(tid & 3) * 4 + c];
        *(float4*)(og + c * 4) = q;
        float4 xa = *(const float4*)(xg + c * 4);
        float a;
        a = q.x - xa.x; lossLocal = fmaf(a, a, lossLocal);
        a = q.y - xa.y; lossLocal = fmaf(a, a, lossLocal);
        a = q.z - xa.z; lossLocal = fmaf(a, a, lossLocal);
        a = q.w - xa.w; lossLocal = fmaf(a, a, lossLocal);
    }

    // block-reduce loss -> partial store; LAST block reduces all partials
#pragma unroll
    for (int off = 32; off; off >>= 1) lossLocal += __shfl_down(lossLocal, off, 64);
    if (lane == 0) swl[wid] = lossLocal;
    __syncthreads();
    if (tid == 0) {
        float s = 0.f;
#pragma unroll
        for (int i = 0; i < 8; ++i) s += swl[i];
        ws[WS_PART + blockIdx.x] = s;
        __threadfence();                               // partial visible device-wide
        unsigned prev = atomicAdd((unsigned*)ws, 1u);  // one atomic per block
        lastFlag = (prev == (unsigned)(NBLK - 1)) ? 1 : 0;
    }
    __syncthreads();
    if (lastFlag) {
        __threadfence();                  // acquire: see all partials
        float s = ws[WS_PART + tid];      // 512 threads, one partial each
#pragma unroll
        for (int off = 32; off; off >>= 1) s += __shfl_down(s, off, 64);
        if (lane == 0) swl[wid] = s;
        __syncthreads();
        if (tid == 0) {
            float total = 0.f;
#pragma unroll
            for (int i = 0; i < 8; ++i) total += swl[i];
            out[(size_t)NVEC * DIM] = 2.0f * total / (float)((size_t)NVEC * DIM);
        }
    }
}

extern "C" void kernel_launch(void* const* d_in, const int* in_sizes, int n_in,
                              void* d_out, int out_size, void* d_ws, size_t ws_size,
                              hipStream_t stream) {
    const float* x   = (const float*)d_in[0];
    const float* emb = (const float*)d_in[1];
    float* out = (float*)d_out;
    float* ws  = (float*)d_ws;

    prep_kernel<<<dim3(17), dim3(512), 0, stream>>>(emb, ws);
    vq_kernel<<<dim3(NBLK), dim3(512), 0, stream>>>(x, ws, out, ws);
}

// Round 18
// 39.345 us; speedup vs baseline: 1.5825x; 1.5825x over previous
//
#include <hip/hip_runtime.h>

// B*H*W = 65536 vectors, dim 64, 512 codes
#define NVEC 65536
#define DIM 64
#define KCODES 512
#define VPB 128       // vectors per block
#define NBLK 512      // NVEC / VPB
#define ELS 2048.0f   // residual pre-scale (avoids fp16 denormals)
#define INV_ELS (1.0f / 2048.0f)
#define BIAS 8.0f     // score bias -> positive floats, uint-sortable
#define GAP_THR 2.5e-4f // rescore guard: > 2x (split-fp16 1.5e-5 + 5-bit mask 3e-5)

typedef _Float16 f16x8 __attribute__((ext_vector_type(8)));
typedef float    f32x4 __attribute__((ext_vector_type(4)));
typedef unsigned long long u64;

// ws layout (floats):
#define WS_EN   4                   // [4..516) codebook norms (exact)
#define WS_EH   1024                // [1024..17408) hi fp16 B-fragments (pre-scaled by -2)
#define WS_EL   (1024 + 16384)      // [17408..33792) residual fp16 B-fragments (pre-scaled by -2*ELS)
#define WS_PART 33792               // [33792..34304) per-block loss partials (512)
#define WS_EMBT 34816               // [34816..67584) embT[k][d]

// Prep (17 blocks x 512): b=0 exact norms; b=1..8 MFMA B-fragments with the
// -2 factor folded in (exact: *2 lossless in fp16); b=9..16 emb -> embT.
__global__ __launch_bounds__(512, 1) void prep_kernel(const float* __restrict__ emb,
                                                      float* __restrict__ ws) {
    const int tid = threadIdx.x;
    const int b   = blockIdx.x;
    if (b == 0) {
        float s = 0.f;
#pragma unroll
        for (int d = 0; d < DIM; ++d) { float v = emb[d * KCODES + tid]; s = fmaf(v, v, s); }
        ws[WS_EN + tid] = s;
    } else if (b <= 8) {
        const int fl = (b - 1) * 512 + tid;            // fragment-lane id, 0..4095
        const int ct = fl >> 7, s5 = (fl >> 6) & 1, l = fl & 63;
        const int k  = ct * 16 + (l & 15);             // B col
        const int d0 = s5 * 32 + (l >> 4) * 8;         // B k-rows (d)
        f16x8 eh, el;
#pragma unroll
        for (int e = 0; e < 8; ++e) {
            float v = emb[(d0 + e) * KCODES + k];
            _Float16 h = (_Float16)v;
            _Float16 l16 = (_Float16)((v - (float)h) * ELS);
            eh[e] = -(h + h);      // -2*h, exact
            el[e] = -(l16 + l16);  // -2*l, exact
        }
        ((f16x8*)(ws + WS_EH))[fl] = eh;
        ((f16x8*)(ws + WS_EL))[fl] = el;
    } else {
        __shared__ float tl[64][65];
        const int kt = b - 9;          // k-tile 0..7
        const int r  = tid >> 3;       // 0..63
        const int g  = tid & 7;
#pragma unroll
        for (int i = 0; i < 8; ++i)
            tl[r][g * 8 + i] = emb[r * KCODES + kt * 64 + g * 8 + i];
        __syncthreads();
#pragma unroll
        for (int i = 0; i < 8; ++i)
            ws[WS_EMBT + (kt * 64 + r) * 64 + g * 8 + i] = tl[g * 8 + i][r];
    }
}

// Main: 512 thr = 8 waves, VPB=128, grid 512 -> 4 waves/SIMD, one round.
// R15 structure with ONE change: the B-fragment register pipeline is a
// 4-set rotation (A,B,C,D). A set reloaded after COMPUTE(t) is consumed at
// COMPUTE(t+4), i.e. a 3-COMPUTE window (~450-600 cyc) that fully covers L2
// latency -- R15's swap-free 2-set scheme had only a 1-COMPUTE WAR-limited
// window (~150-200 cyc), stalling every COMPUTE head. Packed-u32 top-2,
// u64 lex merge, GAP_THR exact rescore, embT epilogue, separate finish
// kernel (R17 lesson: NEVER device fences for cross-block reduction).
__global__ __launch_bounds__(512, 2) void vq_kernel(const float* __restrict__ x,
                                                    const float* __restrict__ ws_ro,
                                                    float* __restrict__ out,
                                                    float* __restrict__ part) {
    __shared__ f16x8 zhS[VPB][8];   // [v][u], u = (d>>3) ^ (v&7)  (bank swizzle)
    __shared__ f16x8 zlS[VPB][8];
    __shared__ float enS8[KCODES];  // en + BIAS (scan C-init)
    __shared__ int   cand[VPB][2];
    __shared__ float sdfm[VPB][2];  // biased masked scores
    __shared__ float exd[VPB][2];
    __shared__ int   bksel[VPB];
    __shared__ float swl[8];

    const int tid  = threadIdx.x;
    const int wid  = tid >> 6;            // 0..7
    const int lane = tid & 63;
    const size_t xbase = (size_t)blockIdx.x * VPB * DIM;

    enS8[tid] = ws_ro[WS_EN + tid] + BIAS;   // biased copy for the scan

    // x-block -> fp16 hi + scaled residual into swizzled LDS (4 thr/vector)
    {
        const int v  = tid >> 2;          // 0..127
        const int d0 = (tid & 3) * 16;
        const float* xp = x + xbase + v * DIM + d0;
        float4 a = *(const float4*)(xp);
        float4 b = *(const float4*)(xp + 4);
        float4 c = *(const float4*)(xp + 8);
        float4 e = *(const float4*)(xp + 12);
        float t0[8] = {a.x, a.y, a.z, a.w, b.x, b.y, b.z, b.w};
        float t1[8] = {c.x, c.y, c.z, c.w, e.x, e.y, e.z, e.w};
        f16x8 h0, l0, h1, l1;
#pragma unroll
        for (int i = 0; i < 8; ++i) {
            _Float16 h = (_Float16)t0[i]; h0[i] = h; l0[i] = (_Float16)((t0[i] - (float)h) * ELS);
            _Float16 g = (_Float16)t1[i]; h1[i] = g; l1[i] = (_Float16)((t1[i] - (float)g) * ELS);
        }
        const int u0 = ((d0 >> 3))     ^ (v & 7);
        const int u1 = ((d0 >> 3) + 1) ^ (v & 7);
        zhS[v][u0] = h0; zhS[v][u1] = h1;
        zlS[v][u0] = l0; zlS[v][u1] = l1;
    }
    __syncthreads();

    // A-fragments: row = lane&15 (vector), k = (lane>>4)*8 + e (+32 for 2nd)
    const int vb  = wid * 16;
    const int col = lane & 15;
    const int g4  = lane >> 4;
    const int vA  = vb + col;
    const int sw  = vA & 7;
    f16x8 ah0 = zhS[vA][(g4)     ^ sw];
    f16x8 ah1 = zhS[vA][(4 + g4) ^ sw];
    f16x8 al0 = zlS[vA][(g4)     ^ sw];
    f16x8 al1 = zlS[vA][(4 + g4) ^ sw];

    const f16x8* ehp = (const f16x8*)(ws_ro + WS_EH);
    const f16x8* elp = (const f16x8*)(ws_ro + WS_EL);

    unsigned b1[4] = {~0u, ~0u, ~0u, ~0u};
    unsigned b2[4] = {~0u, ~0u, ~0u, ~0u};

    // 4-set rotating pipeline: tiles t, t+1, t+2, t+3 in flight
    f16x8 Ah0 = ehp[lane],        Ah1 = ehp[64 + lane];
    f16x8 Al0 = elp[lane],        Al1 = elp[64 + lane];
    f16x8 Bh0 = ehp[128 + lane],  Bh1 = ehp[192 + lane];
    f16x8 Bl0 = elp[128 + lane],  Bl1 = elp[192 + lane];
    f16x8 Ch0 = ehp[256 + lane],  Ch1 = ehp[320 + lane];
    f16x8 Cl0 = elp[256 + lane],  Cl1 = elp[320 + lane];
    f16x8 Dh0 = ehp[384 + lane],  Dh1 = ehp[448 + lane];
    f16x8 Dl0 = elp[384 + lane],  Dl1 = elp[448 + lane];
    int onx = 512 + lane;                 // fragment index of tile ct+4

#define COMPUTE(EN, T, H0, H1, L0, L1) { \
        f32x4 acch  = {EN, EN, EN, EN}; \
        f32x4 accm1 = {0.f, 0.f, 0.f, 0.f}; \
        f32x4 accm2 = {0.f, 0.f, 0.f, 0.f}; \
        acch  = __builtin_amdgcn_mfma_f32_16x16x32_f16(ah0, H0, acch,  0, 0, 0); \
        acch  = __builtin_amdgcn_mfma_f32_16x16x32_f16(ah1, H1, acch,  0, 0, 0); \
        accm1 = __builtin_amdgcn_mfma_f32_16x16x32_f16(al0, H0, accm1, 0, 0, 0); \
        accm1 = __builtin_amdgcn_mfma_f32_16x16x32_f16(ah0, L0, accm1, 0, 0, 0); \
        accm2 = __builtin_amdgcn_mfma_f32_16x16x32_f16(al1, H1, accm2, 0, 0, 0); \
        accm2 = __builtin_amdgcn_mfma_f32_16x16x32_f16(ah1, L1, accm2, 0, 0, 0); \
        _Pragma("unroll") \
        for (int j = 0; j < 4; ++j) { \
            float scb = fmaf(accm1[j] + accm2[j], INV_ELS, acch[j]); \
            unsigned u = (__float_as_uint(scb) & 0xFFFFFFE0u) | (unsigned)(T); \
            b2[j] = min(b2[j], max(u, b1[j])); \
            b1[j] = min(b1[j], u); \
        } }

#pragma unroll 1
    for (int ct = 0; ct < 32; ct += 4) {
        // batch the 4 en reads so LDS latency overlaps the MFMAs
        const float e0 = enS8[(ct + 0) * 16 + col];
        const float e1 = enS8[(ct + 1) * 16 + col];
        const float e2 = enS8[(ct + 2) * 16 + col];
        const float e3 = enS8[(ct + 3) * 16 + col];
        COMPUTE(e0, ct, Ah0, Ah1, Al0, Al1)
        // reload set A with tile ct+4 (tail iters read harmless ws data)
        Ah0 = ehp[onx];       Ah1 = ehp[onx + 64];
        Al0 = elp[onx];       Al1 = elp[onx + 64];
        COMPUTE(e1, ct + 1, Bh0, Bh1, Bl0, Bl1)
        Bh0 = ehp[onx + 128]; Bh1 = ehp[onx + 192];
        Bl0 = elp[onx + 128]; Bl1 = elp[onx + 192];
        COMPUTE(e2, ct + 2, Ch0, Ch1, Cl0, Cl1)
        Ch0 = ehp[onx + 256]; Ch1 = ehp[onx + 320];
        Cl0 = elp[onx + 256]; Cl1 = elp[onx + 320];
        COMPUTE(e3, ct + 3, Dh0, Dh1, Dl0, Dl1)
        Dh0 = ehp[onx + 384]; Dh1 = ehp[onx + 448];
        Dl0 = elp[onx + 384]; Dl1 = elp[onx + 448];
        onx += 512;
    }
#undef COMPUTE

    // rebuild (masked-dist, k) as u64 and lex-merge top-2 across 16 lanes
    u64 q1[4], q2[4];
#pragma unroll
    for (int j = 0; j < 4; ++j) {
        q1[j] = ((u64)(b1[j] & 0xFFFFFFE0u) << 32) | (unsigned)((b1[j] & 31u) * 16 + col);
        q2[j] = ((u64)(b2[j] & 0xFFFFFFE0u) << 32) | (unsigned)((b2[j] & 31u) * 16 + col);
    }
#pragma unroll
    for (int m = 1; m <= 8; m <<= 1) {
#pragma unroll
        for (int j = 0; j < 4; ++j) {
            u64 qa = __shfl_xor(q1[j], m);
            u64 qb = __shfl_xor(q2[j], m);
            u64 lo = q1[j] < qa ? q1[j] : qa;
            u64 hi = q1[j] < qa ? qa : q1[j];
            u64 s2 = q2[j] < qb ? q2[j] : qb;
            q1[j] = lo;
            q2[j] = hi < s2 ? hi : s2;
        }
    }
    {
        const int j = lane & 15;
        if (j < 4) {                      // static-index extraction (rule #20)
            const int v = vb + g4 * 4 + j;
            u64 s1 = j == 0 ? q1[0] : j == 1 ? q1[1] : j == 2 ? q1[2] : q1[3];
            u64 s2 = j == 0 ? q2[0] : j == 1 ? q2[1] : j == 2 ? q2[2] : q2[3];
            sdfm[v][0] = __uint_as_float((unsigned)(s1 >> 32));  // biased, masked
            sdfm[v][1] = __uint_as_float((unsigned)(s2 >> 32));
            cand[v][0] = (int)(s1 & 0x1FFu);
            cand[v][1] = (int)(s2 & 0x1FFu);
        }
    }
    __syncthreads();

    // conditional exact rescore (reference-exact chain; exact en from ws)
    if (tid < 2 * VPB) {
        const int v = tid >> 1, cc = tid & 1;
        float res = sdfm[v][cc];          // biased fallback (consistent pair)
        if (sdfm[v][1] - sdfm[v][0] <= GAP_THR) {
            const int k = cand[v][cc];
            const float* xr = x + xbase + v * DIM;
            const float* er = ws_ro + WS_EMBT + k * 64;
            float zn = 0.f, dot = 0.f;
#pragma unroll
            for (int d = 0; d < DIM; ++d) {
                float xv = xr[d];
                zn  = fmaf(xv, xv, zn);
                dot = fmaf(xv, er[d], dot);
            }
            res = fmaf(-2.0f, dot, zn + ws_ro[WS_EN + k]);
        }
        exd[v][cc] = res;
    }
    __syncthreads();
    if (tid < VPB) {
        const int k0 = cand[tid][0], k1 = cand[tid][1];
        const float d0 = exd[tid][0], d1 = exd[tid][1];
        const bool take2 = (d1 < d0) || (d1 == d0 && k1 < k0);
        bksel[tid] = take2 ? k1 : k0;
    }
    __syncthreads();

    // epilogue: thread -> (vector v16, dim-block j16); q from embT rows
    const int v16 = tid >> 2;             // 0..127
    const int j16 = (tid & 3) * 16;
    const int bk  = bksel[v16];
    const int gvec = blockIdx.x * VPB + v16;
    const float*  xg  = x + (size_t)gvec * DIM + j16;
    float*        og  = out + (size_t)gvec * DIM + j16;
    const float4* et4 = (const float4*)(ws_ro + WS_EMBT + bk * 64);

    float lossLocal = 0.f;
#pragma unroll
    for (int c = 0; c < 4; ++c) {
        float4 q  = et4[(tid & 3) * 4 + c];
        *(float4*)(og + c * 4) = q;
        float4 xa = *(const float4*)(xg + c * 4);
        float a;
        a = q.x - xa.x; lossLocal = fmaf(a, a, lossLocal);
        a = q.y - xa.y; lossLocal = fmaf(a, a, lossLocal);
        a = q.z - xa.z; lossLocal = fmaf(a, a, lossLocal);
        a = q.w - xa.w; lossLocal = fmaf(a, a, lossLocal);
    }

    // block-reduce loss -> one partial store per block (no atomics/fences)
#pragma unroll
    for (int off = 32; off; off >>= 1) lossLocal += __shfl_down(lossLocal, off, 64);
    if (lane == 0) swl[wid] = lossLocal;
    __syncthreads();
    if (tid == 0) {
        float s = 0.f;
#pragma unroll
        for (int i = 0; i < 8; ++i) s += swl[i];
        part[WS_PART + blockIdx.x] = s;
    }
}

// Finish: reduce 512 per-block partials, write the loss element.
__global__ __launch_bounds__(256, 1) void finish_kernel(const float* __restrict__ part,
                                                        float* __restrict__ out) {
    __shared__ float sw[4];
    const int tid = threadIdx.x, lane = tid & 63, wid = tid >> 6;
    float s = part[WS_PART + tid] + part[WS_PART + tid + 256];
#pragma unroll
    for (int off = 32; off; off >>= 1) s += __shfl_down(s, off, 64);
    if (lane == 0) sw[wid] = s;
    __syncthreads();
    if (tid == 0) {
        float total = sw[0] + sw[1] + sw[2] + sw[3];
        out[(size_t)NVEC * DIM] = 2.0f * total / (float)((size_t)NVEC * DIM);
    }
}

extern "C" void kernel_launch(void* const* d_in, const int* in_sizes, int n_in,
                              void* d_out, int out_size, void* d_ws, size_t ws_size,
                              hipStream_t stream) {
    const float* x   = (const float*)d_in[0];
    const float* emb = (const float*)d_in[1];
    float* out = (float*)d_out;
    float* ws  = (float*)d_ws;

    prep_kernel<<<dim3(17), dim3(512), 0, stream>>>(emb, ws);
    vq_kernel<<<dim3(NBLK), dim3(512), 0, stream>>>(x, ws, out, ws);
    finish_kernel<<<dim3(1), dim3(256), 0, stream>>>(ws, out);
}